// Round 6
// baseline (253.925 us; speedup 1.0000x reference)
//
#include <hip/hip_runtime.h>

// Problem constants (from reference)
constexpr int N_CONTEXT = 9;
constexpr int C         = 26;                 // N_INPUT
constexpr int WINDOW    = 2 * N_CONTEXT + 1;  // 19
constexpr int BATCH     = 64;
constexpr int TIME      = 2000;
constexpr int ROW       = WINDOW * C;         // 494 floats per output row
constexpr int ROW2      = ROW / 2;            // 247 float2 columns per row
constexpr int C2        = C / 2;              // 13 float2 per time step

// Tile: one block handles T_TILE consecutive output rows (batch-uniform).
constexpr int T_TILE    = 40;                    // 40 | 2000
constexpr int LDS_ROWS  = T_TILE + WINDOW - 1;   // 58 time steps staged
constexpr int LDS_F2    = LDS_ROWS * C2;         // 754 float2 (6 KB; last tile row
                                                 // needs floats up to 39*26+493=1507=LDS_F2*2-1 ✓)
constexpr int BLOCK     = 256;
constexpr int NBLOCKS   = BATCH * TIME / T_TILE; // 3200
constexpr int BATCH_F2  = TIME * C2;             // 26000 float2 per batch

__global__ __launch_bounds__(BLOCK)
void CreateOverlappingWindows_84963043050043_kernel(const float* __restrict__ x,
                                                    float* __restrict__ out) {
    __shared__ float2 lds2[LDS_F2];
    const int blk = blockIdx.x;
    const int tid = threadIdx.x;
    const int r0  = blk * T_TILE;            // first output row (multiple of 40)
    const int b   = r0 / TIME;               // batch (tile is batch-uniform)
    const int lo2 = b * BATCH_F2;            // valid float2-index range for batch
    // (r0-9)*26 is even (26*odd/even) and ≡2 mod 4 -> float2 index is exact,
    // and x2[] accesses are 8B-aligned.
    const int base2 = ((r0 - N_CONTEXT) * C) >> 1;
    const float2* x2 = reinterpret_cast<const float2*>(x);

    // Phase 1: stage x[b, r0-9 .. r0+T_TILE+8, :] as float2, zeros materialized
    // for out-of-batch times (validity = single unsigned range check; both
    // halves of a float2 share it since lo2/hi2 boundaries are float2-aligned).
    #pragma unroll
    for (int it = 0; it < (LDS_F2 + BLOCK - 1) / BLOCK; ++it) {
        int idx = tid + it * BLOCK;
        if (idx < LDS_F2) {
            int g = base2 + idx;
            float2 v = make_float2(0.0f, 0.0f);
            if ((unsigned)(g - lo2) < (unsigned)BATCH_F2) v = x2[g];
            lds2[idx] = v;
        }
    }
    __syncthreads();

    // Phase 2: thread = column pair, loop = rows. out[(r0+lt)*494 + 2*tid .. +1]
    // <- lds float (lt*26 + 2*tid) = lds2[lt*13 + tid]. Per-iteration work is
    // ONE ds_read_b64 (16-bit imm offset, stride-2 banks = b64 issue floor)
    // + ONE independent global_store_dwordx2 (address += 247). No index math,
    // no straddle, no masking — all 40 iterations independent.
    if (tid < ROW2) {
        float2* o2 = reinterpret_cast<float2*>(out) + (size_t)r0 * ROW2 + tid;
        #pragma unroll
        for (int lt = 0; lt < T_TILE; ++lt) {
            o2[(size_t)lt * ROW2] = lds2[lt * C2 + tid];
        }
    }
}

extern "C" void kernel_launch(void* const* d_in, const int* in_sizes, int n_in,
                              void* d_out, int out_size, void* d_ws, size_t ws_size,
                              hipStream_t stream) {
    const float* x = (const float*)d_in[0];
    float* out = (float*)d_out;
    CreateOverlappingWindows_84963043050043_kernel<<<NBLOCKS, BLOCK, 0, stream>>>(x, out);
}